// Round 6
// baseline (1787.379 us; speedup 1.0000x reference)
//
#include <hip/hip_runtime.h>

#define N_NODESC 100000
#define N_EDGESC 1600000
#define IN_DIMC 128
#define HIDC 64
#define N_GRAPHSC 512
#define NB1C ((N_NODESC + 255) / 256)  // 391

__device__ __forceinline__ unsigned enc_f32(float f) {
  unsigned b = __float_as_uint(f);
  return (b & 0x80000000u) ? ~b : (b | 0x80000000u);
}
__device__ __forceinline__ float dec_f32(unsigned k) {
  unsigned b = (k & 0x80000000u) ? (k & 0x7fffffffu) : ~k;
  return __uint_as_float(b);
}

// ---------------- setup kernels ----------------

__global__ void zero_kernel(int* cnt, unsigned* smax, float* ssum, int* cntg, unsigned* pooled) {
  int i = blockIdx.x * blockDim.x + threadIdx.x;
  if (i < N_NODESC) cnt[i] = 0;
  if (i < N_GRAPHSC) { smax[i] = 0u; ssum[i] = 0.f; cntg[i] = 0; }
  if (i < N_GRAPHSC * HIDC) pooled[i] = 0u;
}

// degree count; atomic return value IS the within-row slot -> no atomics needed in fill
__global__ void deg_kernel(const int* __restrict__ dstv, int* __restrict__ cnt,
                           int* __restrict__ slot) {
  int e = blockIdx.x * blockDim.x + threadIdx.x;
  if (e < N_EDGESC) slot[e] = atomicAdd(&cnt[dstv[e]], 1);
}

// 3-kernel exclusive scan of cnt[] -> row_start[]; scan3 also computes dinv
__global__ void scan1_kernel(const int* __restrict__ cnt, int* __restrict__ partial) {
  __shared__ int sdata[256];
  int t = threadIdx.x;
  int i = blockIdx.x * 256 + t;
  int v = (i < N_NODESC) ? cnt[i] : 0;
  sdata[t] = v;
  __syncthreads();
  for (int s = 128; s > 0; s >>= 1) {
    if (t < s) sdata[t] += sdata[t + s];
    __syncthreads();
  }
  if (t == 0) partial[blockIdx.x] = sdata[0];
}

__global__ void scan2_kernel(const int* __restrict__ partial, int* __restrict__ blockoff) {
  __shared__ int sdata[512];
  int t = threadIdx.x;
  int v = (t < NB1C) ? partial[t] : 0;
  sdata[t] = v;
  __syncthreads();
  for (int off = 1; off < 512; off <<= 1) {
    int add = (t >= off) ? sdata[t - off] : 0;
    __syncthreads();
    sdata[t] += add;
    __syncthreads();
  }
  if (t < NB1C) blockoff[t] = sdata[t] - v;  // exclusive
}

__global__ void scan3_kernel(const int* __restrict__ cnt, const int* __restrict__ blockoff,
                             int* __restrict__ row_start, float* __restrict__ dinv) {
  __shared__ int sdata[256];
  int t = threadIdx.x;
  int i = blockIdx.x * 256 + t;
  int v = (i < N_NODESC) ? cnt[i] : 0;
  sdata[t] = v;
  __syncthreads();
  for (int off = 1; off < 256; off <<= 1) {
    int add = (t >= off) ? sdata[t - off] : 0;
    __syncthreads();
    sdata[t] += add;
    __syncthreads();
  }
  int excl = sdata[t] - v + blockoff[blockIdx.x];
  if (i < N_NODESC) {
    row_start[i] = excl;
    dinv[i] = rsqrtf((float)v + 1.0f);
  }
  if (i == N_NODESC) row_start[N_NODESC] = excl;  // == E
}

// atomic-free fill: position = row_start[dst] + slot[e]
__global__ void fill_kernel(const int* __restrict__ srcv, const int* __restrict__ dstv,
                            const int* __restrict__ slot, const int* __restrict__ row_start,
                            int* __restrict__ csr_src) {
  int e = blockIdx.x * blockDim.x + threadIdx.x;
  if (e >= N_EDGESC) return;
  int d = dstv[e];
  int p = row_start[d] + slot[e];
  __builtin_nontemporal_store(srcv[e], &csr_src[p]);
}

// ---------------- GCN layer kernels ----------------

// ts[r][:] = (X[r][:] @ W) * dinv[r]   -- one THREAD per row.
// Lane i owns row base+i fully in registers (x[K]); W[k][j0..j0+15] is
// wave-uniform -> scalar loads -> v_fmac with SGPR operand. No DS/shuffle ops.
// acc[16] x 4 column-tiles keeps VGPR pressure low.
template <int K>
__global__ void __launch_bounds__(256, (K == 128 ? 2 : 4))
gemm_rows_kernel(const float* __restrict__ X, const float* __restrict__ W,
                 const float* __restrict__ dinv, float* __restrict__ T) {
  int r = blockIdx.x * blockDim.x + threadIdx.x;
  bool valid = r < N_NODESC;
  float x[K];
  if (valid) {
    const float4* __restrict__ xr = (const float4*)(X + (size_t)r * K);
#pragma unroll
    for (int c = 0; c < K / 4; ++c) {
      float4 q = xr[c];
      x[4 * c + 0] = q.x;
      x[4 * c + 1] = q.y;
      x[4 * c + 2] = q.z;
      x[4 * c + 3] = q.w;
    }
  }
  float dv = valid ? dinv[r] : 0.f;
  for (int j0 = 0; j0 < HIDC; j0 += 16) {  // 4 column tiles
    float acc[16];
#pragma unroll
    for (int t = 0; t < 16; ++t) acc[t] = 0.f;
#pragma unroll
    for (int k = 0; k < K; ++k) {
      const float* __restrict__ wr = W + k * HIDC + j0;  // wave-uniform
#pragma unroll
      for (int t = 0; t < 16; ++t) acc[t] = fmaf(x[k], wr[t], acc[t]);
    }
    if (valid) {
      float4* __restrict__ Tr = (float4*)(T + (size_t)r * HIDC + j0);
#pragma unroll
      for (int c = 0; c < 4; ++c) {
        float4 o;
        o.x = acc[4 * c + 0] * dv;
        o.y = acc[4 * c + 1] * dv;
        o.z = acc[4 * c + 2] * dv;
        o.w = acc[4 * c + 3] * dv;
        Tr[c] = o;
      }
    }
  }
}

// h[i][j] = relu(dinv[i] * (ts[i][j] + sum_{e in-edges of i} ts[src[e]][j]) + b[j])
__global__ void gather_kernel(const float* __restrict__ ts, const float* __restrict__ dinv,
                              const int* __restrict__ row_start, const int* __restrict__ csr_src,
                              const float* __restrict__ bias, float* __restrict__ h) {
  int lane = threadIdx.x & 63;
  int node = (blockIdx.x * blockDim.x + threadIdx.x) >> 6;
  if (node >= N_NODESC) return;
  int rs = row_start[node];
  int re = row_start[node + 1];
  float sum = ts[node * HIDC + lane];  // self-loop term
  int e = rs;
  for (; e + 8 <= re; e += 8) {
    int s0 = csr_src[e], s1 = csr_src[e + 1], s2 = csr_src[e + 2], s3 = csr_src[e + 3];
    int s4 = csr_src[e + 4], s5 = csr_src[e + 5], s6 = csr_src[e + 6], s7 = csr_src[e + 7];
    float v0 = ts[s0 * HIDC + lane];
    float v1 = ts[s1 * HIDC + lane];
    float v2 = ts[s2 * HIDC + lane];
    float v3 = ts[s3 * HIDC + lane];
    float v4 = ts[s4 * HIDC + lane];
    float v5 = ts[s5 * HIDC + lane];
    float v6 = ts[s6 * HIDC + lane];
    float v7 = ts[s7 * HIDC + lane];
    sum += ((v0 + v1) + (v2 + v3)) + ((v4 + v5) + (v6 + v7));
  }
  for (; e + 4 <= re; e += 4) {
    int s0 = csr_src[e], s1 = csr_src[e + 1], s2 = csr_src[e + 2], s3 = csr_src[e + 3];
    float v0 = ts[s0 * HIDC + lane];
    float v1 = ts[s1 * HIDC + lane];
    float v2 = ts[s2 * HIDC + lane];
    float v3 = ts[s3 * HIDC + lane];
    sum += (v0 + v1) + (v2 + v3);
  }
  for (; e < re; ++e) sum += ts[csr_src[e] * HIDC + lane];
  h[node * HIDC + lane] = fmaxf(sum * dinv[node] + bias[lane], 0.f);
}

// ---------------- readout kernels ----------------

__global__ void score_kernel(const float* __restrict__ closeness, const float* __restrict__ Wc,
                             const float* __restrict__ bc, const int* __restrict__ batch,
                             float* __restrict__ sbuf, unsigned* __restrict__ smax,
                             int* __restrict__ cntg) {
  int i = blockIdx.x * blockDim.x + threadIdx.x;
  int lane = threadIdx.x & 63;
  bool valid = i < N_NODESC;
  float s = 0.f;
  int g = 0;
  unsigned key = 0u;
  if (valid) {
    s = bc[0];
#pragma unroll
    for (int k = 0; k < 5; ++k) s += closeness[i * 5 + k] * Wc[k];
    sbuf[i] = s;
    g = batch[i];
    key = enc_f32(s);
  }
  bool fullwave = ((i - lane) + 64) <= N_NODESC;
  int g0 = __shfl(g, 0);
  int g63 = __shfl(g, 63);
  if (fullwave && g0 == g63) {
    unsigned kmax = key;
#pragma unroll
    for (int off = 32; off > 0; off >>= 1) kmax = max(kmax, (unsigned)__shfl_xor((int)kmax, off));
    if (lane == 0) {
      atomicMax(&smax[g], kmax);
      atomicAdd(&cntg[g], 64);
    }
  } else if (valid) {
    atomicMax(&smax[g], key);
    atomicAdd(&cntg[g], 1);
  }
}

__global__ void expsum_kernel(const float* __restrict__ sbuf, const unsigned* __restrict__ smax,
                              const int* __restrict__ batch, float* __restrict__ ebuf,
                              float* __restrict__ ssum) {
  int i = blockIdx.x * blockDim.x + threadIdx.x;
  int lane = threadIdx.x & 63;
  bool valid = i < N_NODESC;
  float ev = 0.f;
  int g = 0;
  if (valid) {
    g = batch[i];
    float m = dec_f32(smax[g]);
    ev = expf(sbuf[i] - m);
    ebuf[i] = ev;
  }
  bool fullwave = ((i - lane) + 64) <= N_NODESC;
  int g0 = __shfl(g, 0);
  int g63 = __shfl(g, 63);
  if (fullwave && g0 == g63) {
    float tot = ev;
#pragma unroll
    for (int off = 32; off > 0; off >>= 1) tot += __shfl_xor(tot, off);
    if (lane == 0) unsafeAtomicAdd(&ssum[g], tot);
  } else if (valid) {
    unsafeAtomicAdd(&ssum[g], ev);
  }
}

#define POOL_CHUNK 32
__global__ void pool_kernel(const float* __restrict__ h, const float* __restrict__ ebuf,
                            const float* __restrict__ ssum, const int* __restrict__ cntg,
                            const int* __restrict__ batch, unsigned* __restrict__ pooled) {
  int lane = threadIdx.x & 63;
  int wave = (blockIdx.x * blockDim.x + threadIdx.x) >> 6;
  int nw = (gridDim.x * blockDim.x) >> 6;
  for (int base = wave * POOL_CHUNK; base < N_NODESC; base += nw * POOL_CHUNK) {
    int end = min(base + POOL_CHUNK, N_NODESC);
    int curg = batch[base];
    float vmax = 0.f;  // all values nonneg (relu * positive weight)
    for (int i = base; i < end; ++i) {
      int g = batch[i];
      if (g != curg) {
        atomicMax(&pooled[curg * HIDC + lane], __float_as_uint(vmax));
        vmax = 0.f;
        curg = g;
      }
      float w = ebuf[i] / ssum[g] * (float)cntg[g];
      vmax = fmaxf(vmax, w * h[i * HIDC + lane]);
    }
    atomicMax(&pooled[curg * HIDC + lane], __float_as_uint(vmax));
  }
}

__global__ void mlp_kernel(const unsigned* __restrict__ pooled, const float* __restrict__ Wa1,
                           const float* __restrict__ ba1, const float* __restrict__ Wa2,
                           const float* __restrict__ ba2, float* __restrict__ out) {
  int lane = threadIdx.x & 63;
  int g = (blockIdx.x * blockDim.x + threadIdx.x) >> 6;
  if (g >= N_GRAPHSC) return;
  float p = __uint_as_float(pooled[g * HIDC + lane]);
  float o = 0.f;
#pragma unroll
  for (int t = 0; t < 16; ++t) {
    float prod = p * Wa1[lane * 16 + t];
#pragma unroll
    for (int off = 32; off > 0; off >>= 1) prod += __shfl_xor(prod, off);
    float a = fmaxf(prod + ba1[t], 0.f);
    o += a * Wa2[t];
  }
  if (lane == 0) out[g] = o + ba2[0];
}

// ---------------- launch ----------------

extern "C" void kernel_launch(void* const* d_in, const int* in_sizes, int n_in,
                              void* d_out, int out_size, void* d_ws, size_t ws_size,
                              hipStream_t stream) {
  const float* x = (const float*)d_in[0];
  const int* ei = (const int*)d_in[1];
  const float* closeness = (const float*)d_in[2];
  const int* batch = (const int*)d_in[3];
  const float* W1 = (const float*)d_in[5];
  const float* b1 = (const float*)d_in[6];
  const float* W2 = (const float*)d_in[7];
  const float* b2 = (const float*)d_in[8];
  const float* W3 = (const float*)d_in[9];
  const float* b3 = (const float*)d_in[10];
  const float* Wc = (const float*)d_in[11];
  const float* bc = (const float*)d_in[12];
  const float* Wa1 = (const float*)d_in[13];
  const float* ba1 = (const float*)d_in[14];
  const float* Wa2 = (const float*)d_in[15];
  const float* ba2 = (const float*)d_in[16];
  float* out = (float*)d_out;
  const int* srcv = ei;
  const int* dstv = ei + N_EDGESC;

  char* ws = (char*)d_ws;
  size_t off = 0;
  auto alloc = [&](size_t bytes) -> void* {
    void* p = ws + off;
    off = (off + bytes + 255) & ~(size_t)255;
    return p;
  };
  float* tbuf = (float*)alloc(sizeof(float) * N_NODESC * HIDC);   // 25.6 MB
  float* hbuf = (float*)alloc(sizeof(float) * N_NODESC * HIDC);   // 25.6 MB
  int* cnt = (int*)alloc(sizeof(int) * N_NODESC);
  int* row_start = (int*)alloc(sizeof(int) * (N_NODESC + 1));
  int* slot = (int*)alloc(sizeof(int) * N_EDGESC);                // 6.4 MB
  int* csr_src = (int*)alloc(sizeof(int) * N_EDGESC);             // 6.4 MB
  float* dinv = (float*)alloc(sizeof(float) * N_NODESC);
  float* sbuf = (float*)alloc(sizeof(float) * N_NODESC);
  float* ebuf = (float*)alloc(sizeof(float) * N_NODESC);
  unsigned* smax = (unsigned*)alloc(sizeof(unsigned) * N_GRAPHSC);
  float* ssum = (float*)alloc(sizeof(float) * N_GRAPHSC);
  int* cntg = (int*)alloc(sizeof(int) * N_GRAPHSC);
  unsigned* pooled = (unsigned*)alloc(sizeof(unsigned) * N_GRAPHSC * HIDC);
  int* partial = (int*)alloc(sizeof(int) * NB1C);
  int* blockoff = (int*)alloc(sizeof(int) * NB1C);

  const int B = 256;
  int gN = (N_NODESC + B - 1) / B;      // 391
  int gE = (N_EDGESC + B - 1) / B;      // 6250
  int gGather = (N_NODESC * 64) / B;    // 25000

  zero_kernel<<<gN, B, 0, stream>>>(cnt, smax, ssum, cntg, pooled);
  deg_kernel<<<gE, B, 0, stream>>>(dstv, cnt, slot);
  scan1_kernel<<<NB1C, B, 0, stream>>>(cnt, partial);
  scan2_kernel<<<1, 512, 0, stream>>>(partial, blockoff);
  scan3_kernel<<<NB1C, B, 0, stream>>>(cnt, blockoff, row_start, dinv);
  fill_kernel<<<gE, B, 0, stream>>>(srcv, dstv, slot, row_start, csr_src);

  // layer 1 (K=128, single pass)
  gemm_rows_kernel<IN_DIMC><<<gN, B, 0, stream>>>(x, W1, dinv, tbuf);
  gather_kernel<<<gGather, B, 0, stream>>>(tbuf, dinv, row_start, csr_src, b1, hbuf);
  // layer 2
  gemm_rows_kernel<HIDC><<<gN, B, 0, stream>>>(hbuf, W2, dinv, tbuf);
  gather_kernel<<<gGather, B, 0, stream>>>(tbuf, dinv, row_start, csr_src, b2, hbuf);
  // layer 3
  gemm_rows_kernel<HIDC><<<gN, B, 0, stream>>>(hbuf, W3, dinv, tbuf);
  gather_kernel<<<gGather, B, 0, stream>>>(tbuf, dinv, row_start, csr_src, b3, hbuf);

  // readout
  score_kernel<<<gN, B, 0, stream>>>(closeness, Wc, bc, batch, sbuf, smax, cntg);
  expsum_kernel<<<gN, B, 0, stream>>>(sbuf, smax, batch, ebuf, ssum);
  pool_kernel<<<782, B, 0, stream>>>(hbuf, ebuf, ssum, cntg, batch, pooled);
  mlp_kernel<<<(N_GRAPHSC * 64) / B, B, 0, stream>>>(pooled, Wa1, ba1, Wa2, ba2, out);
}

// Round 7
// 777.089 us; speedup vs baseline: 2.3001x; 2.3001x over previous
//
#include <hip/hip_runtime.h>

#define N_NODESC 100000
#define N_EDGESC 1600000
#define IN_DIMC 128
#define HIDC 64
#define N_GRAPHSC 512
#define NB1C ((N_NODESC + 255) / 256)  // 391

__device__ __forceinline__ unsigned enc_f32(float f) {
  unsigned b = __float_as_uint(f);
  return (b & 0x80000000u) ? ~b : (b | 0x80000000u);
}
__device__ __forceinline__ float dec_f32(unsigned k) {
  unsigned b = (k & 0x80000000u) ? (k & 0x7fffffffu) : ~k;
  return __uint_as_float(b);
}

// ---------------- setup kernels ----------------

__global__ void zero_kernel(int* cnt, unsigned* smax, float* ssum, int* cntg, unsigned* pooled) {
  int i = blockIdx.x * blockDim.x + threadIdx.x;
  if (i < N_NODESC) cnt[i] = 0;
  if (i < N_GRAPHSC) { smax[i] = 0u; ssum[i] = 0.f; cntg[i] = 0; }
  if (i < N_GRAPHSC * HIDC) pooled[i] = 0u;
}

// degree count; atomic return value IS the within-row slot -> no atomics needed in fill
__global__ void deg_kernel(const int* __restrict__ dstv, int* __restrict__ cnt,
                           int* __restrict__ slot) {
  int e = blockIdx.x * blockDim.x + threadIdx.x;
  if (e < N_EDGESC) slot[e] = atomicAdd(&cnt[dstv[e]], 1);
}

// 3-kernel exclusive scan of cnt[] -> row_start[]; scan3 also computes dinv
__global__ void scan1_kernel(const int* __restrict__ cnt, int* __restrict__ partial) {
  __shared__ int sdata[256];
  int t = threadIdx.x;
  int i = blockIdx.x * 256 + t;
  int v = (i < N_NODESC) ? cnt[i] : 0;
  sdata[t] = v;
  __syncthreads();
  for (int s = 128; s > 0; s >>= 1) {
    if (t < s) sdata[t] += sdata[t + s];
    __syncthreads();
  }
  if (t == 0) partial[blockIdx.x] = sdata[0];
}

__global__ void scan2_kernel(const int* __restrict__ partial, int* __restrict__ blockoff) {
  __shared__ int sdata[512];
  int t = threadIdx.x;
  int v = (t < NB1C) ? partial[t] : 0;
  sdata[t] = v;
  __syncthreads();
  for (int off = 1; off < 512; off <<= 1) {
    int add = (t >= off) ? sdata[t - off] : 0;
    __syncthreads();
    sdata[t] += add;
    __syncthreads();
  }
  if (t < NB1C) blockoff[t] = sdata[t] - v;  // exclusive
}

__global__ void scan3_kernel(const int* __restrict__ cnt, const int* __restrict__ blockoff,
                             int* __restrict__ row_start, float* __restrict__ dinv) {
  __shared__ int sdata[256];
  int t = threadIdx.x;
  int i = blockIdx.x * 256 + t;
  int v = (i < N_NODESC) ? cnt[i] : 0;
  sdata[t] = v;
  __syncthreads();
  for (int off = 1; off < 256; off <<= 1) {
    int add = (t >= off) ? sdata[t - off] : 0;
    __syncthreads();
    sdata[t] += add;
    __syncthreads();
  }
  int excl = sdata[t] - v + blockoff[blockIdx.x];
  if (i < N_NODESC) {
    row_start[i] = excl;
    dinv[i] = rsqrtf((float)v + 1.0f);
  }
  if (i == N_NODESC) row_start[N_NODESC] = excl;  // == E
}

// atomic-free fill: position = row_start[dst] + slot[e]
__global__ void fill_kernel(const int* __restrict__ srcv, const int* __restrict__ dstv,
                            const int* __restrict__ slot, const int* __restrict__ row_start,
                            int* __restrict__ csr_src) {
  int e = blockIdx.x * blockDim.x + threadIdx.x;
  if (e >= N_EDGESC) return;
  int d = dstv[e];
  int p = row_start[d] + slot[e];
  __builtin_nontemporal_store(srcv[e], &csr_src[p]);
}

// ---------------- GCN layer kernels ----------------

// One 64-wide K-chunk of ts = (X @ W) * dinv, wave per row.
// Row index forced SCALAR via readfirstlane -> X row address is SGPR-only ->
// compiler emits s_load (scalar cache) for xr[k]; inner loop is pure
// v_fmac(dst, s_x, v_wcol). No DS ops, no vector broadcast loads, no arrays.
template <int LDX, bool FIRST, bool LAST>
__global__ void __launch_bounds__(256, 4)
gemm_pass_kernel(const float* __restrict__ X, const float* __restrict__ W,
                 const float* __restrict__ dinv, float* __restrict__ T) {
  int lane = threadIdx.x & 63;
  float wcol[64];
#pragma unroll
  for (int k = 0; k < 64; ++k) wcol[k] = W[k * HIDC + lane];
  int wave = (blockIdx.x * blockDim.x + threadIdx.x) >> 6;
  int nwaves = (gridDim.x * blockDim.x) >> 6;
  int wave_s = __builtin_amdgcn_readfirstlane(wave);  // scalar wave id
  for (int r = wave_s; r < N_NODESC; r += nwaves) {   // r stays scalar
    const float* __restrict__ xr = X + (size_t)r * LDX;  // SGPR-only address
    float a0 = 0.f, a1 = 0.f, a2 = 0.f, a3 = 0.f;
#pragma unroll
    for (int k = 0; k < 64; k += 4) {
      a0 = fmaf(xr[k + 0], wcol[k + 0], a0);
      a1 = fmaf(xr[k + 1], wcol[k + 1], a1);
      a2 = fmaf(xr[k + 2], wcol[k + 2], a2);
      a3 = fmaf(xr[k + 3], wcol[k + 3], a3);
    }
    float res = (a0 + a1) + (a2 + a3);
    if (!FIRST) res += T[r * HIDC + lane];
    if (LAST) res *= dinv[r];
    T[r * HIDC + lane] = res;
  }
}

// h[i][j] = relu(dinv[i] * (ts[i][j] + sum_{e in-edges of i} ts[src[e]][j]) + b[j])
__global__ void gather_kernel(const float* __restrict__ ts, const float* __restrict__ dinv,
                              const int* __restrict__ row_start, const int* __restrict__ csr_src,
                              const float* __restrict__ bias, float* __restrict__ h) {
  int lane = threadIdx.x & 63;
  int node = (blockIdx.x * blockDim.x + threadIdx.x) >> 6;
  if (node >= N_NODESC) return;
  int rs = row_start[node];
  int re = row_start[node + 1];
  float sum = ts[node * HIDC + lane];  // self-loop term
  int e = rs;
  for (; e + 8 <= re; e += 8) {
    int s0 = csr_src[e], s1 = csr_src[e + 1], s2 = csr_src[e + 2], s3 = csr_src[e + 3];
    int s4 = csr_src[e + 4], s5 = csr_src[e + 5], s6 = csr_src[e + 6], s7 = csr_src[e + 7];
    float v0 = ts[s0 * HIDC + lane];
    float v1 = ts[s1 * HIDC + lane];
    float v2 = ts[s2 * HIDC + lane];
    float v3 = ts[s3 * HIDC + lane];
    float v4 = ts[s4 * HIDC + lane];
    float v5 = ts[s5 * HIDC + lane];
    float v6 = ts[s6 * HIDC + lane];
    float v7 = ts[s7 * HIDC + lane];
    sum += ((v0 + v1) + (v2 + v3)) + ((v4 + v5) + (v6 + v7));
  }
  for (; e + 4 <= re; e += 4) {
    int s0 = csr_src[e], s1 = csr_src[e + 1], s2 = csr_src[e + 2], s3 = csr_src[e + 3];
    float v0 = ts[s0 * HIDC + lane];
    float v1 = ts[s1 * HIDC + lane];
    float v2 = ts[s2 * HIDC + lane];
    float v3 = ts[s3 * HIDC + lane];
    sum += (v0 + v1) + (v2 + v3);
  }
  for (; e < re; ++e) sum += ts[csr_src[e] * HIDC + lane];
  h[node * HIDC + lane] = fmaxf(sum * dinv[node] + bias[lane], 0.f);
}

// ---------------- readout kernels ----------------

__global__ void score_kernel(const float* __restrict__ closeness, const float* __restrict__ Wc,
                             const float* __restrict__ bc, const int* __restrict__ batch,
                             float* __restrict__ sbuf, unsigned* __restrict__ smax,
                             int* __restrict__ cntg) {
  int i = blockIdx.x * blockDim.x + threadIdx.x;
  int lane = threadIdx.x & 63;
  bool valid = i < N_NODESC;
  float s = 0.f;
  int g = 0;
  unsigned key = 0u;
  if (valid) {
    s = bc[0];
#pragma unroll
    for (int k = 0; k < 5; ++k) s += closeness[i * 5 + k] * Wc[k];
    sbuf[i] = s;
    g = batch[i];
    key = enc_f32(s);
  }
  bool fullwave = ((i - lane) + 64) <= N_NODESC;
  int g0 = __shfl(g, 0);
  int g63 = __shfl(g, 63);
  if (fullwave && g0 == g63) {
    unsigned kmax = key;
#pragma unroll
    for (int off = 32; off > 0; off >>= 1) kmax = max(kmax, (unsigned)__shfl_xor((int)kmax, off));
    if (lane == 0) {
      atomicMax(&smax[g], kmax);
      atomicAdd(&cntg[g], 64);
    }
  } else if (valid) {
    atomicMax(&smax[g], key);
    atomicAdd(&cntg[g], 1);
  }
}

__global__ void expsum_kernel(const float* __restrict__ sbuf, const unsigned* __restrict__ smax,
                              const int* __restrict__ batch, float* __restrict__ ebuf,
                              float* __restrict__ ssum) {
  int i = blockIdx.x * blockDim.x + threadIdx.x;
  int lane = threadIdx.x & 63;
  bool valid = i < N_NODESC;
  float ev = 0.f;
  int g = 0;
  if (valid) {
    g = batch[i];
    float m = dec_f32(smax[g]);
    ev = expf(sbuf[i] - m);
    ebuf[i] = ev;
  }
  bool fullwave = ((i - lane) + 64) <= N_NODESC;
  int g0 = __shfl(g, 0);
  int g63 = __shfl(g, 63);
  if (fullwave && g0 == g63) {
    float tot = ev;
#pragma unroll
    for (int off = 32; off > 0; off >>= 1) tot += __shfl_xor(tot, off);
    if (lane == 0) unsafeAtomicAdd(&ssum[g], tot);
  } else if (valid) {
    unsafeAtomicAdd(&ssum[g], ev);
  }
}

#define POOL_CHUNK 32
__global__ void pool_kernel(const float* __restrict__ h, const float* __restrict__ ebuf,
                            const float* __restrict__ ssum, const int* __restrict__ cntg,
                            const int* __restrict__ batch, unsigned* __restrict__ pooled) {
  int lane = threadIdx.x & 63;
  int wave = (blockIdx.x * blockDim.x + threadIdx.x) >> 6;
  int nw = (gridDim.x * blockDim.x) >> 6;
  for (int base = wave * POOL_CHUNK; base < N_NODESC; base += nw * POOL_CHUNK) {
    int end = min(base + POOL_CHUNK, N_NODESC);
    int curg = batch[base];
    float vmax = 0.f;  // all values nonneg (relu * positive weight)
    for (int i = base; i < end; ++i) {
      int g = batch[i];
      if (g != curg) {
        atomicMax(&pooled[curg * HIDC + lane], __float_as_uint(vmax));
        vmax = 0.f;
        curg = g;
      }
      float w = ebuf[i] / ssum[g] * (float)cntg[g];
      vmax = fmaxf(vmax, w * h[i * HIDC + lane]);
    }
    atomicMax(&pooled[curg * HIDC + lane], __float_as_uint(vmax));
  }
}

__global__ void mlp_kernel(const unsigned* __restrict__ pooled, const float* __restrict__ Wa1,
                           const float* __restrict__ ba1, const float* __restrict__ Wa2,
                           const float* __restrict__ ba2, float* __restrict__ out) {
  int lane = threadIdx.x & 63;
  int g = (blockIdx.x * blockDim.x + threadIdx.x) >> 6;
  if (g >= N_GRAPHSC) return;
  float p = __uint_as_float(pooled[g * HIDC + lane]);
  float o = 0.f;
#pragma unroll
  for (int t = 0; t < 16; ++t) {
    float prod = p * Wa1[lane * 16 + t];
#pragma unroll
    for (int off = 32; off > 0; off >>= 1) prod += __shfl_xor(prod, off);
    float a = fmaxf(prod + ba1[t], 0.f);
    o += a * Wa2[t];
  }
  if (lane == 0) out[g] = o + ba2[0];
}

// ---------------- launch ----------------

extern "C" void kernel_launch(void* const* d_in, const int* in_sizes, int n_in,
                              void* d_out, int out_size, void* d_ws, size_t ws_size,
                              hipStream_t stream) {
  const float* x = (const float*)d_in[0];
  const int* ei = (const int*)d_in[1];
  const float* closeness = (const float*)d_in[2];
  const int* batch = (const int*)d_in[3];
  const float* W1 = (const float*)d_in[5];
  const float* b1 = (const float*)d_in[6];
  const float* W2 = (const float*)d_in[7];
  const float* b2 = (const float*)d_in[8];
  const float* W3 = (const float*)d_in[9];
  const float* b3 = (const float*)d_in[10];
  const float* Wc = (const float*)d_in[11];
  const float* bc = (const float*)d_in[12];
  const float* Wa1 = (const float*)d_in[13];
  const float* ba1 = (const float*)d_in[14];
  const float* Wa2 = (const float*)d_in[15];
  const float* ba2 = (const float*)d_in[16];
  float* out = (float*)d_out;
  const int* srcv = ei;
  const int* dstv = ei + N_EDGESC;

  char* ws = (char*)d_ws;
  size_t off = 0;
  auto alloc = [&](size_t bytes) -> void* {
    void* p = ws + off;
    off = (off + bytes + 255) & ~(size_t)255;
    return p;
  };
  float* tbuf = (float*)alloc(sizeof(float) * N_NODESC * HIDC);   // 25.6 MB
  float* hbuf = (float*)alloc(sizeof(float) * N_NODESC * HIDC);   // 25.6 MB
  int* cnt = (int*)alloc(sizeof(int) * N_NODESC);
  int* row_start = (int*)alloc(sizeof(int) * (N_NODESC + 1));
  int* slot = (int*)alloc(sizeof(int) * N_EDGESC);                // 6.4 MB
  int* csr_src = (int*)alloc(sizeof(int) * N_EDGESC);             // 6.4 MB
  float* dinv = (float*)alloc(sizeof(float) * N_NODESC);
  float* sbuf = (float*)alloc(sizeof(float) * N_NODESC);
  float* ebuf = (float*)alloc(sizeof(float) * N_NODESC);
  unsigned* smax = (unsigned*)alloc(sizeof(unsigned) * N_GRAPHSC);
  float* ssum = (float*)alloc(sizeof(float) * N_GRAPHSC);
  int* cntg = (int*)alloc(sizeof(int) * N_GRAPHSC);
  unsigned* pooled = (unsigned*)alloc(sizeof(unsigned) * N_GRAPHSC * HIDC);
  int* partial = (int*)alloc(sizeof(int) * NB1C);
  int* blockoff = (int*)alloc(sizeof(int) * NB1C);

  const int B = 256;
  int gN = (N_NODESC + B - 1) / B;      // 391
  int gE = (N_EDGESC + B - 1) / B;      // 6250
  int gGather = (N_NODESC * 64) / B;    // 25000

  zero_kernel<<<gN, B, 0, stream>>>(cnt, smax, ssum, cntg, pooled);
  deg_kernel<<<gE, B, 0, stream>>>(dstv, cnt, slot);
  scan1_kernel<<<NB1C, B, 0, stream>>>(cnt, partial);
  scan2_kernel<<<1, 512, 0, stream>>>(partial, blockoff);
  scan3_kernel<<<NB1C, B, 0, stream>>>(cnt, blockoff, row_start, dinv);
  fill_kernel<<<gE, B, 0, stream>>>(srcv, dstv, slot, row_start, csr_src);

  // layer 1: split-K (two 64-wide chunks)
  gemm_pass_kernel<IN_DIMC, true, false><<<1024, B, 0, stream>>>(x, W1, dinv, tbuf);
  gemm_pass_kernel<IN_DIMC, false, true><<<1024, B, 0, stream>>>(x + 64, W1 + 64 * HIDC, dinv, tbuf);
  gather_kernel<<<gGather, B, 0, stream>>>(tbuf, dinv, row_start, csr_src, b1, hbuf);
  // layer 2
  gemm_pass_kernel<HIDC, true, true><<<1024, B, 0, stream>>>(hbuf, W2, dinv, tbuf);
  gather_kernel<<<gGather, B, 0, stream>>>(tbuf, dinv, row_start, csr_src, b2, hbuf);
  // layer 3
  gemm_pass_kernel<HIDC, true, true><<<1024, B, 0, stream>>>(hbuf, W3, dinv, tbuf);
  gather_kernel<<<gGather, B, 0, stream>>>(tbuf, dinv, row_start, csr_src, b3, hbuf);

  // readout
  score_kernel<<<gN, B, 0, stream>>>(closeness, Wc, bc, batch, sbuf, smax, cntg);
  expsum_kernel<<<gN, B, 0, stream>>>(sbuf, smax, batch, ebuf, ssum);
  pool_kernel<<<782, B, 0, stream>>>(hbuf, ebuf, ssum, cntg, batch, pooled);
  mlp_kernel<<<(N_GRAPHSC * 64) / B, B, 0, stream>>>(pooled, Wa1, ba1, Wa2, ba2, out);
}

// Round 8
// 574.559 us; speedup vs baseline: 3.1109x; 1.3525x over previous
//
#include <hip/hip_runtime.h>

#define N_NODESC 100000
#define N_EDGESC 1600000
#define IN_DIMC 128
#define HIDC 64
#define N_GRAPHSC 512
#define NB1C ((N_NODESC + 255) / 256)  // 391

__device__ __forceinline__ unsigned enc_f32(float f) {
  unsigned b = __float_as_uint(f);
  return (b & 0x80000000u) ? ~b : (b | 0x80000000u);
}
__device__ __forceinline__ float dec_f32(unsigned k) {
  unsigned b = (k & 0x80000000u) ? (k & 0x7fffffffu) : ~k;
  return __uint_as_float(b);
}

// ---------------- setup kernels ----------------

__global__ void zero_kernel(int* cnt, unsigned* smax, float* ssum, int* cntg, unsigned* pooled) {
  int i = blockIdx.x * blockDim.x + threadIdx.x;
  if (i < N_NODESC) cnt[i] = 0;
  if (i < N_GRAPHSC) { smax[i] = 0u; ssum[i] = 0.f; cntg[i] = 0; }
  if (i < N_GRAPHSC * HIDC) pooled[i] = 0u;
}

// degree count; atomic return value IS the within-row slot -> no atomics needed in fill
__global__ void deg_kernel(const int* __restrict__ dstv, int* __restrict__ cnt,
                           int* __restrict__ slot) {
  int e = blockIdx.x * blockDim.x + threadIdx.x;
  if (e < N_EDGESC) slot[e] = atomicAdd(&cnt[dstv[e]], 1);
}

// 3-kernel exclusive scan of cnt[] -> row_start[]; scan3 also computes dinv
__global__ void scan1_kernel(const int* __restrict__ cnt, int* __restrict__ partial) {
  __shared__ int sdata[256];
  int t = threadIdx.x;
  int i = blockIdx.x * 256 + t;
  int v = (i < N_NODESC) ? cnt[i] : 0;
  sdata[t] = v;
  __syncthreads();
  for (int s = 128; s > 0; s >>= 1) {
    if (t < s) sdata[t] += sdata[t + s];
    __syncthreads();
  }
  if (t == 0) partial[blockIdx.x] = sdata[0];
}

__global__ void scan2_kernel(const int* __restrict__ partial, int* __restrict__ blockoff) {
  __shared__ int sdata[512];
  int t = threadIdx.x;
  int v = (t < NB1C) ? partial[t] : 0;
  sdata[t] = v;
  __syncthreads();
  for (int off = 1; off < 512; off <<= 1) {
    int add = (t >= off) ? sdata[t - off] : 0;
    __syncthreads();
    sdata[t] += add;
    __syncthreads();
  }
  if (t < NB1C) blockoff[t] = sdata[t] - v;  // exclusive
}

__global__ void scan3_kernel(const int* __restrict__ cnt, const int* __restrict__ blockoff,
                             int* __restrict__ row_start, float* __restrict__ dinv) {
  __shared__ int sdata[256];
  int t = threadIdx.x;
  int i = blockIdx.x * 256 + t;
  int v = (i < N_NODESC) ? cnt[i] : 0;
  sdata[t] = v;
  __syncthreads();
  for (int off = 1; off < 256; off <<= 1) {
    int add = (t >= off) ? sdata[t - off] : 0;
    __syncthreads();
    sdata[t] += add;
    __syncthreads();
  }
  int excl = sdata[t] - v + blockoff[blockIdx.x];
  if (i < N_NODESC) {
    row_start[i] = excl;
    dinv[i] = rsqrtf((float)v + 1.0f);
  }
  if (i == N_NODESC) row_start[N_NODESC] = excl;  // == E
}

// atomic-free fill: position = row_start[dst] + slot[e]
__global__ void fill_kernel(const int* __restrict__ srcv, const int* __restrict__ dstv,
                            const int* __restrict__ slot, const int* __restrict__ row_start,
                            int* __restrict__ csr_src) {
  int e = blockIdx.x * blockDim.x + threadIdx.x;
  if (e >= N_EDGESC) return;
  int d = dstv[e];
  int p = row_start[d] + slot[e];
  __builtin_nontemporal_store(srcv[e], &csr_src[p]);
}

// ---------------- GCN layer kernels ----------------

// Tiled fp32 GEMM: T[tile] = (X[tile] @ W) * dinv, tile = 128 rows x 64 cols.
// xs is staged TRANSPOSED (xs[k][r], ld=132: 16B-aligned b128 reads; per-k row
// slices are 16-lane broadcasts -> conflict-free). W tile 64x64 staged linearly.
// Each thread: 8 rows x 4 cols in registers; per k: 3 ds_read_b128 + 32 fmac.
#define GT_M 128
#define XS_LD 132
template <int KT>
__global__ void __launch_bounds__(256, 3)
gemm_tile_kernel(const float* __restrict__ X, const float* __restrict__ W,
                 const float* __restrict__ dinv, float* __restrict__ T) {
  __shared__ float xs[64 * XS_LD];  // 33.8 KB
  __shared__ float ws[64 * 64];     // 16 KB
  int t = threadIdx.x;
  int base = blockIdx.x * GT_M;
  int r0 = (t >> 4) * 8;  // row group 0..15 -> 8 rows
  int c0 = (t & 15) * 4;  // col group 0..15 -> 4 cols
  float acc[8][4];
#pragma unroll
  for (int i = 0; i < 8; ++i)
#pragma unroll
    for (int j = 0; j < 4; ++j) acc[i][j] = 0.f;

  int kq = (t & 15) * 4;  // staging k-quad
  int rr = t >> 4;        // staging row base

  for (int kb = 0; kb < KT; kb += 64) {
    if (kb) __syncthreads();
    // stage X tile transposed: 128 rows x 64 ks
#pragma unroll
    for (int it = 0; it < 8; ++it) {
      int r = rr + it * 16;
      int grow = base + r;
      if (grow >= N_NODESC) grow = N_NODESC - 1;
      float4 q = *(const float4*)(X + (size_t)grow * KT + kb + kq);
      xs[(kq + 0) * XS_LD + r] = q.x;
      xs[(kq + 1) * XS_LD + r] = q.y;
      xs[(kq + 2) * XS_LD + r] = q.z;
      xs[(kq + 3) * XS_LD + r] = q.w;
    }
    // stage W tile: linear 16 KB copy
#pragma unroll
    for (int it = 0; it < 4; ++it) {
      int idx = (it * 256 + t) * 4;
      *(float4*)(ws + idx) = *(const float4*)(W + (size_t)kb * HIDC + idx);
    }
    __syncthreads();
#pragma unroll 8
    for (int k = 0; k < 64; ++k) {
      float4 xa = *(const float4*)(xs + k * XS_LD + r0);
      float4 xb = *(const float4*)(xs + k * XS_LD + r0 + 4);
      float4 wf = *(const float4*)(ws + k * 64 + c0);
      float xf[8] = {xa.x, xa.y, xa.z, xa.w, xb.x, xb.y, xb.z, xb.w};
      float wv[4] = {wf.x, wf.y, wf.z, wf.w};
#pragma unroll
      for (int i = 0; i < 8; ++i)
#pragma unroll
        for (int j = 0; j < 4; ++j) acc[i][j] = fmaf(xf[i], wv[j], acc[i][j]);
    }
  }
  // epilogue: scale by dinv, coalesced float4 stores
#pragma unroll
  for (int i = 0; i < 8; ++i) {
    int row = base + r0 + i;
    if (row < N_NODESC) {
      float dv = dinv[row];
      float4 o;
      o.x = acc[i][0] * dv;
      o.y = acc[i][1] * dv;
      o.z = acc[i][2] * dv;
      o.w = acc[i][3] * dv;
      *(float4*)(T + (size_t)row * HIDC + c0) = o;
    }
  }
}

// h[i][j] = relu(dinv[i] * (ts[i][j] + sum_{e in-edges of i} ts[src[e]][j]) + b[j])
__global__ void gather_kernel(const float* __restrict__ ts, const float* __restrict__ dinv,
                              const int* __restrict__ row_start, const int* __restrict__ csr_src,
                              const float* __restrict__ bias, float* __restrict__ h) {
  int lane = threadIdx.x & 63;
  int node = (blockIdx.x * blockDim.x + threadIdx.x) >> 6;
  if (node >= N_NODESC) return;
  int rs = row_start[node];
  int re = row_start[node + 1];
  float sum = ts[node * HIDC + lane];  // self-loop term
  int e = rs;
  for (; e + 8 <= re; e += 8) {
    int s0 = csr_src[e], s1 = csr_src[e + 1], s2 = csr_src[e + 2], s3 = csr_src[e + 3];
    int s4 = csr_src[e + 4], s5 = csr_src[e + 5], s6 = csr_src[e + 6], s7 = csr_src[e + 7];
    float v0 = ts[s0 * HIDC + lane];
    float v1 = ts[s1 * HIDC + lane];
    float v2 = ts[s2 * HIDC + lane];
    float v3 = ts[s3 * HIDC + lane];
    float v4 = ts[s4 * HIDC + lane];
    float v5 = ts[s5 * HIDC + lane];
    float v6 = ts[s6 * HIDC + lane];
    float v7 = ts[s7 * HIDC + lane];
    sum += ((v0 + v1) + (v2 + v3)) + ((v4 + v5) + (v6 + v7));
  }
  for (; e + 4 <= re; e += 4) {
    int s0 = csr_src[e], s1 = csr_src[e + 1], s2 = csr_src[e + 2], s3 = csr_src[e + 3];
    float v0 = ts[s0 * HIDC + lane];
    float v1 = ts[s1 * HIDC + lane];
    float v2 = ts[s2 * HIDC + lane];
    float v3 = ts[s3 * HIDC + lane];
    sum += (v0 + v1) + (v2 + v3);
  }
  for (; e < re; ++e) sum += ts[csr_src[e] * HIDC + lane];
  h[node * HIDC + lane] = fmaxf(sum * dinv[node] + bias[lane], 0.f);
}

// ---------------- readout kernels ----------------

__global__ void score_kernel(const float* __restrict__ closeness, const float* __restrict__ Wc,
                             const float* __restrict__ bc, const int* __restrict__ batch,
                             float* __restrict__ sbuf, unsigned* __restrict__ smax,
                             int* __restrict__ cntg) {
  int i = blockIdx.x * blockDim.x + threadIdx.x;
  int lane = threadIdx.x & 63;
  bool valid = i < N_NODESC;
  float s = 0.f;
  int g = 0;
  unsigned key = 0u;
  if (valid) {
    s = bc[0];
#pragma unroll
    for (int k = 0; k < 5; ++k) s += closeness[i * 5 + k] * Wc[k];
    sbuf[i] = s;
    g = batch[i];
    key = enc_f32(s);
  }
  bool fullwave = ((i - lane) + 64) <= N_NODESC;
  int g0 = __shfl(g, 0);
  int g63 = __shfl(g, 63);
  if (fullwave && g0 == g63) {
    unsigned kmax = key;
#pragma unroll
    for (int off = 32; off > 0; off >>= 1) kmax = max(kmax, (unsigned)__shfl_xor((int)kmax, off));
    if (lane == 0) {
      atomicMax(&smax[g], kmax);
      atomicAdd(&cntg[g], 64);
    }
  } else if (valid) {
    atomicMax(&smax[g], key);
    atomicAdd(&cntg[g], 1);
  }
}

__global__ void expsum_kernel(const float* __restrict__ sbuf, const unsigned* __restrict__ smax,
                              const int* __restrict__ batch, float* __restrict__ ebuf,
                              float* __restrict__ ssum) {
  int i = blockIdx.x * blockDim.x + threadIdx.x;
  int lane = threadIdx.x & 63;
  bool valid = i < N_NODESC;
  float ev = 0.f;
  int g = 0;
  if (valid) {
    g = batch[i];
    float m = dec_f32(smax[g]);
    ev = expf(sbuf[i] - m);
    ebuf[i] = ev;
  }
  bool fullwave = ((i - lane) + 64) <= N_NODESC;
  int g0 = __shfl(g, 0);
  int g63 = __shfl(g, 63);
  if (fullwave && g0 == g63) {
    float tot = ev;
#pragma unroll
    for (int off = 32; off > 0; off >>= 1) tot += __shfl_xor(tot, off);
    if (lane == 0) unsafeAtomicAdd(&ssum[g], tot);
  } else if (valid) {
    unsafeAtomicAdd(&ssum[g], ev);
  }
}

#define POOL_CHUNK 32
__global__ void pool_kernel(const float* __restrict__ h, const float* __restrict__ ebuf,
                            const float* __restrict__ ssum, const int* __restrict__ cntg,
                            const int* __restrict__ batch, unsigned* __restrict__ pooled) {
  int lane = threadIdx.x & 63;
  int wave = (blockIdx.x * blockDim.x + threadIdx.x) >> 6;
  int nw = (gridDim.x * blockDim.x) >> 6;
  for (int base = wave * POOL_CHUNK; base < N_NODESC; base += nw * POOL_CHUNK) {
    int end = min(base + POOL_CHUNK, N_NODESC);
    int curg = batch[base];
    float vmax = 0.f;  // all values nonneg (relu * positive weight)
    for (int i = base; i < end; ++i) {
      int g = batch[i];
      if (g != curg) {
        atomicMax(&pooled[curg * HIDC + lane], __float_as_uint(vmax));
        vmax = 0.f;
        curg = g;
      }
      float w = ebuf[i] / ssum[g] * (float)cntg[g];
      vmax = fmaxf(vmax, w * h[i * HIDC + lane]);
    }
    atomicMax(&pooled[curg * HIDC + lane], __float_as_uint(vmax));
  }
}

__global__ void mlp_kernel(const unsigned* __restrict__ pooled, const float* __restrict__ Wa1,
                           const float* __restrict__ ba1, const float* __restrict__ Wa2,
                           const float* __restrict__ ba2, float* __restrict__ out) {
  int lane = threadIdx.x & 63;
  int g = (blockIdx.x * blockDim.x + threadIdx.x) >> 6;
  if (g >= N_GRAPHSC) return;
  float p = __uint_as_float(pooled[g * HIDC + lane]);
  float o = 0.f;
#pragma unroll
  for (int t = 0; t < 16; ++t) {
    float prod = p * Wa1[lane * 16 + t];
#pragma unroll
    for (int off = 32; off > 0; off >>= 1) prod += __shfl_xor(prod, off);
    float a = fmaxf(prod + ba1[t], 0.f);
    o += a * Wa2[t];
  }
  if (lane == 0) out[g] = o + ba2[0];
}

// ---------------- launch ----------------

extern "C" void kernel_launch(void* const* d_in, const int* in_sizes, int n_in,
                              void* d_out, int out_size, void* d_ws, size_t ws_size,
                              hipStream_t stream) {
  const float* x = (const float*)d_in[0];
  const int* ei = (const int*)d_in[1];
  const float* closeness = (const float*)d_in[2];
  const int* batch = (const int*)d_in[3];
  const float* W1 = (const float*)d_in[5];
  const float* b1 = (const float*)d_in[6];
  const float* W2 = (const float*)d_in[7];
  const float* b2 = (const float*)d_in[8];
  const float* W3 = (const float*)d_in[9];
  const float* b3 = (const float*)d_in[10];
  const float* Wc = (const float*)d_in[11];
  const float* bc = (const float*)d_in[12];
  const float* Wa1 = (const float*)d_in[13];
  const float* ba1 = (const float*)d_in[14];
  const float* Wa2 = (const float*)d_in[15];
  const float* ba2 = (const float*)d_in[16];
  float* out = (float*)d_out;
  const int* srcv = ei;
  const int* dstv = ei + N_EDGESC;

  char* ws = (char*)d_ws;
  size_t off = 0;
  auto alloc = [&](size_t bytes) -> void* {
    void* p = ws + off;
    off = (off + bytes + 255) & ~(size_t)255;
    return p;
  };
  float* tbuf = (float*)alloc(sizeof(float) * N_NODESC * HIDC);   // 25.6 MB
  float* hbuf = (float*)alloc(sizeof(float) * N_NODESC * HIDC);   // 25.6 MB
  int* cnt = (int*)alloc(sizeof(int) * N_NODESC);
  int* row_start = (int*)alloc(sizeof(int) * (N_NODESC + 1));
  int* slot = (int*)alloc(sizeof(int) * N_EDGESC);                // 6.4 MB
  int* csr_src = (int*)alloc(sizeof(int) * N_EDGESC);             // 6.4 MB
  float* dinv = (float*)alloc(sizeof(float) * N_NODESC);
  float* sbuf = (float*)alloc(sizeof(float) * N_NODESC);
  float* ebuf = (float*)alloc(sizeof(float) * N_NODESC);
  unsigned* smax = (unsigned*)alloc(sizeof(unsigned) * N_GRAPHSC);
  float* ssum = (float*)alloc(sizeof(float) * N_GRAPHSC);
  int* cntg = (int*)alloc(sizeof(int) * N_GRAPHSC);
  unsigned* pooled = (unsigned*)alloc(sizeof(unsigned) * N_GRAPHSC * HIDC);
  int* partial = (int*)alloc(sizeof(int) * NB1C);
  int* blockoff = (int*)alloc(sizeof(int) * NB1C);

  const int B = 256;
  int gN = (N_NODESC + B - 1) / B;        // 391
  int gE = (N_EDGESC + B - 1) / B;        // 6250
  int gGather = (N_NODESC * 64) / B;      // 25000
  int gTile = (N_NODESC + GT_M - 1) / GT_M;  // 782

  zero_kernel<<<gN, B, 0, stream>>>(cnt, smax, ssum, cntg, pooled);
  deg_kernel<<<gE, B, 0, stream>>>(dstv, cnt, slot);
  scan1_kernel<<<NB1C, B, 0, stream>>>(cnt, partial);
  scan2_kernel<<<1, 512, 0, stream>>>(partial, blockoff);
  scan3_kernel<<<NB1C, B, 0, stream>>>(cnt, blockoff, row_start, dinv);
  fill_kernel<<<gE, B, 0, stream>>>(srcv, dstv, slot, row_start, csr_src);

  // layer 1 (K=128 handled inside the tile kernel)
  gemm_tile_kernel<IN_DIMC><<<gTile, B, 0, stream>>>(x, W1, dinv, tbuf);
  gather_kernel<<<gGather, B, 0, stream>>>(tbuf, dinv, row_start, csr_src, b1, hbuf);
  // layer 2
  gemm_tile_kernel<HIDC><<<gTile, B, 0, stream>>>(hbuf, W2, dinv, tbuf);
  gather_kernel<<<gGather, B, 0, stream>>>(tbuf, dinv, row_start, csr_src, b2, hbuf);
  // layer 3
  gemm_tile_kernel<HIDC><<<gTile, B, 0, stream>>>(hbuf, W3, dinv, tbuf);
  gather_kernel<<<gGather, B, 0, stream>>>(tbuf, dinv, row_start, csr_src, b3, hbuf);

  // readout
  score_kernel<<<gN, B, 0, stream>>>(closeness, Wc, bc, batch, sbuf, smax, cntg);
  expsum_kernel<<<gN, B, 0, stream>>>(sbuf, smax, batch, ebuf, ssum);
  pool_kernel<<<782, B, 0, stream>>>(hbuf, ebuf, ssum, cntg, batch, pooled);
  mlp_kernel<<<(N_GRAPHSC * 64) / B, B, 0, stream>>>(pooled, Wa1, ba1, Wa2, ba2, out);
}